// Round 9
// baseline (444.805 us; speedup 1.0000x reference)
//
#include <hip/hip_runtime.h>
#include <math.h>

#define NVEH 400000
#define NTOT 500000
#define NEDGE 16000000
#define DT 0.2f
#define SAFE_C 1.5f
#define PARK_C 5.0f
#define RADIUS_C 1.5f
#define DEFV_C 2.5f
#define LIST_CAP 4096     // ids stored in ws; LDS membership path iff count <= this
#define REG_USE 16        // registerized compare path iff count <= this

#define MASK_BLOCKS ((NVEH + 255) / 256)         // 1563
#define MASK_WAVES  (MASK_BLOCKS * 4)            // 6252
#define EDGE_BLOCKS (NEDGE / (256 * 4))          // 15625

typedef int vint4 __attribute__((ext_vector_type(4)));   // nontemporal-load-compatible

// ws layout (bytes):
//   maskArr  @ 0         : NVEH * float = 1,600,000   (only for cnt>LIST_CAP fallback)
//   segdiff  @ 1,600,000 : NVEH * float = 1,600,000   (zeroed by mask_kernel for masked ids)
//   count    @ 3,200,000 : int                         [memset 0 — 4 bytes]
//   done     @ 3,200,008 : int                         (zeroed by mask_kernel block 0)
//   ids      @ 3,200,016 : LIST_CAP * int = 16,384
//   partials @ 3,216,400 : MASK_WAVES * double = 50,016

// Recompute a node's collision-model state directly from inputs.
// g = col7 + R + veh*(|s|+R)  (e0-role),  h = |s| + SAFE  (e1-role)
__device__ __forceinline__ void node_state(
    int n, const float* __restrict__ X,
    const float* __restrict__ yr, const float* __restrict__ yp,
    float& px, float& py, float& rx, float& ry, float& g, float& h)
{
    const float* row = X + (size_t)n * 9;
    float x0 = row[0], x1 = row[1], x7 = row[7];
    if (n < NVEH) {
        float psi = row[2], v = row[3];
        float yr0 = yr[2 * n], yr1 = yr[2 * n + 1], yp0 = yp[2 * n];
        float xt = x0 + v * cosf(psi) * DT;
        float yt = x1 + v * sinf(psi) * DT;
        float vt = 0.99f * v + yr0 * DT;
        float speed = vt + (yp0 - yr0) * DT;
        float as = fabsf(speed);
        px = xt + cosf(yr1) * speed * DT;
        py = yt + sinf(yr1) * speed * DT;
        rx = xt; ry = yt;
        g = x7 + RADIUS_C + as + RADIUS_C;
        h = as + SAFE_C;
    } else {
        float v = row[3];
        px = rx = x0; py = ry = x1;
        g = x7 + RADIUS_C;
        h = fabsf(v) + SAFE_C;
    }
}

__global__ __launch_bounds__(256) void mask_kernel(
    const float* __restrict__ yp, const float* __restrict__ yr,
    const float* __restrict__ X, const float* __restrict__ be,
    float* __restrict__ maskArr, float* __restrict__ segdiff,
    int* __restrict__ countp, int* __restrict__ donep,
    int* __restrict__ ids, double* __restrict__ partials)
{
    __shared__ float sX[256 * 9];                 // stage this block's X rows, coalesced
    int blk0 = blockIdx.x * 256;
    if (blockIdx.x == 0 && threadIdx.x == 0) *donep = 0;   // reset edge completion ctr
    int nrows = NVEH - blk0; if (nrows > 256) nrows = 256;   // 256 or 128 -> *9/4 integral
    {
        int nf4 = (nrows * 9) >> 2;
        const float4* src = (const float4*)(X + (size_t)blk0 * 9);
        for (int t = threadIdx.x; t < nf4; t += 256)
            ((float4*)sX)[t] = src[t];
    }
    __syncthreads();

    int i = blk0 + threadIdx.x;
    double local = 0.0;
    if (i < NVEH) {
        const float* row = sX + threadIdx.x * 9;  // stride-9 LDS: 2-way alias = free
        float x0 = row[0], x1 = row[1], psi = row[2], v = row[3];
        float p4 = row[4], p5 = row[5];
        float2 yrv = ((const float2*)yr)[i];
        float2 ypv = ((const float2*)yp)[i];
        float yr0 = yrv.x, yr1 = yrv.y, yp0 = ypv.x, yp1 = ypv.y;

        // vehicle dynamics (psi_t never consumed downstream -> skipped)
        float xt = x0 + v * cosf(psi) * DT;
        float yt = x1 + v * sinf(psi) * DT;
        float vt = 0.99f * v + yr0 * DT;

        // masks
        float dx = xt - p4, dy = yt - p5;
        bool m1 = (sqrtf(dx * dx + dy * dy) - (PARK_C + fabsf(v))) > 0.0f;
        bool m2 = fabsf(vt) >= (DEFV_C - 1e-5f);
        float sg = (vt > 0.0f) ? 1.0f : ((vt < 0.0f) ? -1.0f : 0.0f);
        bool m3 = sg * (yr0 - yp0) <= 1e-5f;
        bool msk = m1 && m2 && m3;
        maskArr[i] = msk ? 1.0f : 0.0f;
        if (msk) {
            segdiff[i] = 0.0f;                   // only masked entries are ever accumulated/read
            int idx = atomicAdd(countp, 1);
            if (idx < LIST_CAP) ids[idx] = i;
        }

        // edge-independent loss terms
        float t1 = (yr1 - yp1) * 1.25f;          // / BOUND1 (0.8)
        float l1 = t1 * t1;
        float t2 = yr0 - yp0;                    // / BOUND0 (1.0)
        float l21 = t2 * t2;
        float2 bev = ((const float2*)be)[i];
        float b1s = bev.y * 1.25f;
        float l3 = bev.x * bev.x + b1s * b1s;

        local = (double)l1 + (double)((msk ? 0.0f : 1.0f) * l21) + 0.1 * (double)l3;
    }
    // wave-level double reduction -> ONE PLAIN STORE per wave (no atomics)
    for (int off = 32; off > 0; off >>= 1)
        local += __shfl_down(local, off, 64);
    if ((threadIdx.x & 63) == 0)
        partials[blockIdx.x * 4 + (threadIdx.x >> 6)] = local;
}

__device__ __forceinline__ void edge_compute(
    int a, int b,
    const float* __restrict__ X, const float* __restrict__ yr,
    const float* __restrict__ yp, float* __restrict__ segdiff)
{
    float pax, pay, rax, ray, ga, ha;
    float pbx, pby, rbx, rby, gb, hb;
    node_state(a, X, yr, yp, pax, pay, rax, ray, ga, ha);
    node_state(b, X, yr, yp, pbx, pby, rbx, rby, gb, hb);

    float base = ga + hb;    // g[a] + h[b]

    float dxp = pax - pbx, dyp = pay - pby;
    float dp = sqrtf(dxp * dxp + dyp * dyp);
    float lcp = fmaxf(base - dp, 0.0f);

    float dxr = rax - rbx, dyr = ray - rby;
    float dr = sqrtf(dxr * dxr + dyr * dyr);
    float lcr = fmaxf(base - dr, 0.0f);

    float diff = (lcp * lcp + lcp) - (lcr * lcr + lcr);
    if (diff != 0.0f)
        atomicAdd(segdiff + b, diff);
}

__global__ __launch_bounds__(256) void edge_finish_kernel(
    const int* __restrict__ e0p, const int* __restrict__ e1p,
    const float* __restrict__ X, const float* __restrict__ yr,
    const float* __restrict__ yp, const float* __restrict__ maskArr,
    float* __restrict__ segdiff,
    const int* __restrict__ countp, int* __restrict__ donep,
    const int* __restrict__ ids,
    const double* __restrict__ partials, float* __restrict__ out)
{
    __shared__ int s_ids[LIST_CAP];
    __shared__ int s_last;
    int cnt = *countp;
    int base = (blockIdx.x * 256 + threadIdx.x) * 4;   // 4 edges per thread

    if (cnt > 0) {                                     // cnt==0: whole e1 stream is dead
        if (cnt <= LIST_CAP) {
            for (int t = threadIdx.x; t < cnt; t += 256) s_ids[t] = ids[t];
            __syncthreads();
            vint4 bv = __builtin_nontemporal_load((const vint4*)(e1p + base));

            if (cnt <= REG_USE) {
                // branchless registerized membership test (typical: cnt ~ a few)
                int idr[REG_USE];
#pragma unroll
                for (int j = 0; j < REG_USE; ++j)
                    idr[j] = (j < cnt) ? s_ids[j] : -1;

                int bs[4] = {bv.x, bv.y, bv.z, bv.w};
#pragma unroll
                for (int k = 0; k < 4; ++k) {
                    int b = bs[k];
                    bool h = false;
#pragma unroll
                    for (int j = 0; j < REG_USE; ++j) h |= (b == idr[j]);
                    if (h) {
                        int a = e0p[base + k];
                        edge_compute(a, b, X, yr, yp, segdiff);
                    }
                }
            } else {
                // rare: LDS membership loop over up to 4096 ids
                int bs[4] = {bv.x, bv.y, bv.z, bv.w};
#pragma unroll
                for (int k = 0; k < 4; ++k) {
                    int b = bs[k];
                    bool h = false;
                    for (int j = 0; j < cnt; ++j) h |= (b == s_ids[j]);
                    if (h) {
                        int a = e0p[base + k];
                        edge_compute(a, b, X, yr, yp, segdiff);
                    }
                }
            }
        } else {
            // robust fallback: per-edge mask gather (statistically never taken)
            for (int k = 0; k < 4; ++k) {
                int b = e1p[base + k];
                if (b < NVEH && maskArr[b] != 0.0f) {
                    int a = e0p[base + k];
                    edge_compute(a, b, X, yr, yp, segdiff);
                }
            }
        }
    }

    // ---- last-block-done: the final block to retire runs the finish phase ----
    __syncthreads();
    if (threadIdx.x == 0) {
        __threadfence();                              // release segdiff atomics
        int t = atomicAdd(donep, 1);
        s_last = (t == (int)gridDim.x - 1) ? 1 : 0;
    }
    __syncthreads();
    if (!s_last) return;
    __threadfence();                                  // acquire other blocks' writes

    int tid = threadIdx.x;
    double s0 = 0.0, s1 = 0.0, s2 = 0.0, s3 = 0.0;
    for (int j = tid; j < MASK_WAVES; j += 1024) {
        s0 += partials[j];
        if (j + 256 < MASK_WAVES) s1 += partials[j + 256];
        if (j + 512 < MASK_WAVES) s2 += partials[j + 512];
        if (j + 768 < MASK_WAVES) s3 += partials[j + 768];
    }
    double s = (s0 + s1) + (s2 + s3);

    if (cnt <= LIST_CAP) {
        for (int j = tid; j < cnt; j += 256) {
            int i = ids[j];
            float px, py, rx, ry, g, h;
            node_state(i, X, yr, yp, px, py, rx, ry, g, h);
            float bd = sqrtf(px * px + py * py) - sqrtf(rx * rx + ry * ry);
            float d = bd + segdiff[i];
            s += (double)((d >= 0.0f) ? (d * d + d) : d);
        }
    } else {
        for (int i = tid; i < NVEH; i += 256) {
            if (maskArr[i] != 0.0f) {
                float px, py, rx, ry, g, h;
                node_state(i, X, yr, yp, px, py, rx, ry, g, h);
                float bd = sqrtf(px * px + py * py) - sqrtf(rx * rx + ry * ry);
                float d = bd + segdiff[i];
                s += (double)((d >= 0.0f) ? (d * d + d) : d);
            }
        }
    }

    // block reduction (4 waves) — reuse s_ids LDS as double scratch
    double* red = (double*)s_ids;
    for (int off = 32; off > 0; off >>= 1)
        s += __shfl_down(s, off, 64);
    if ((tid & 63) == 0) red[tid >> 6] = s;
    __syncthreads();
    if (tid == 0) {
        double t = red[0] + red[1] + red[2] + red[3];
        out[0] = (float)(t * (1.0 / (double)NVEH));
    }
}

extern "C" void kernel_launch(void* const* d_in, const int* in_sizes, int n_in,
                              void* d_out, int out_size, void* d_ws, size_t ws_size,
                              hipStream_t stream) {
    const float* yp = (const float*)d_in[0];   // y_pred  (NV,2)
    const float* yr = (const float*)d_in[1];   // y_ref   (NV,2)
    const float* X  = (const float*)d_in[2];   // X_cur   (N,9)
    const int*   ed = (const int*)d_in[3];     // edges   (2,E)
    const float* be = (const float*)d_in[4];   // be_static (NV,2)
    float* out = (float*)d_out;

    char* ws = (char*)d_ws;
    float*  maskArr  = (float*) (ws + 0);
    float*  segdiff  = (float*) (ws + 1600000);
    int*    countp   = (int*)   (ws + 3200000);
    int*    donep    = (int*)   (ws + 3200008);
    int*    ids      = (int*)   (ws + 3200016);
    double* partials = (double*)(ws + 3216400);

    // only the 4-byte counter needs pre-zeroing (done is reset by mask_kernel)
    (void)hipMemsetAsync(countp, 0, 4, stream);

    mask_kernel<<<MASK_BLOCKS, 256, 0, stream>>>(
        yp, yr, X, be, maskArr, segdiff, countp, donep, ids, partials);

    edge_finish_kernel<<<EDGE_BLOCKS, 256, 0, stream>>>(
        ed, ed + NEDGE, X, yr, yp, maskArr, segdiff, countp, donep, ids,
        partials, out);
}

// Round 10
// 189.692 us; speedup vs baseline: 2.3449x; 2.3449x over previous
//
#include <hip/hip_runtime.h>
#include <math.h>

#define NVEH 400000
#define NTOT 500000
#define NEDGE 16000000
#define DT 0.2f
#define SAFE_C 1.5f
#define PARK_C 5.0f
#define RADIUS_C 1.5f
#define DEFV_C 2.5f
#define LIST_CAP 4096     // ids stored in ws; LDS membership path iff count <= this
#define REG_USE 16        // registerized compare path iff count <= this

#define MASK_BLOCKS ((NVEH + 255) / 256)         // 1563
#define MASK_WAVES  (MASK_BLOCKS * 4)            // 6252

typedef int vint4 __attribute__((ext_vector_type(4)));   // nontemporal-load-compatible

// ws layout (bytes):
//   maskArr  @ 0         : NVEH * float = 1,600,000   (only for cnt>LIST_CAP fallback)
//   segdiff  @ 1,600,000 : NVEH * float = 1,600,000   (zeroed by mask_kernel for masked ids)
//   count    @ 3,200,000 : int                         [memset 0 — 4 bytes]
//   ids      @ 3,200,016 : LIST_CAP * int = 16,384
//   partials @ 3,216,400 : MASK_WAVES * double = 50,016
//
// NOTE (R9 post-mortem): do NOT fuse finish via last-block-done — 15,625
// device-scope __threadfence + same-address atomics cost ~270 µs of stall.
// Three small dispatches are cheaper than one grid-wide completion protocol.

// Recompute a node's collision-model state directly from inputs.
// g = col7 + R + veh*(|s|+R)  (e0-role),  h = |s| + SAFE  (e1-role)
__device__ __forceinline__ void node_state(
    int n, const float* __restrict__ X,
    const float* __restrict__ yr, const float* __restrict__ yp,
    float& px, float& py, float& rx, float& ry, float& g, float& h)
{
    const float* row = X + (size_t)n * 9;
    float x0 = row[0], x1 = row[1], x7 = row[7];
    if (n < NVEH) {
        float psi = row[2], v = row[3];
        float yr0 = yr[2 * n], yr1 = yr[2 * n + 1], yp0 = yp[2 * n];
        float xt = x0 + v * cosf(psi) * DT;
        float yt = x1 + v * sinf(psi) * DT;
        float vt = 0.99f * v + yr0 * DT;
        float speed = vt + (yp0 - yr0) * DT;
        float as = fabsf(speed);
        px = xt + cosf(yr1) * speed * DT;
        py = yt + sinf(yr1) * speed * DT;
        rx = xt; ry = yt;
        g = x7 + RADIUS_C + as + RADIUS_C;
        h = as + SAFE_C;
    } else {
        float v = row[3];
        px = rx = x0; py = ry = x1;
        g = x7 + RADIUS_C;
        h = fabsf(v) + SAFE_C;
    }
}

__global__ __launch_bounds__(256) void mask_kernel(
    const float* __restrict__ yp, const float* __restrict__ yr,
    const float* __restrict__ X, const float* __restrict__ be,
    float* __restrict__ maskArr, float* __restrict__ segdiff,
    int* __restrict__ countp, int* __restrict__ ids,
    double* __restrict__ partials)
{
    __shared__ float sX[256 * 9];                 // stage this block's X rows, coalesced
    int blk0 = blockIdx.x * 256;
    int nrows = NVEH - blk0; if (nrows > 256) nrows = 256;   // 256 or 128 -> *9/4 integral
    {
        int nf4 = (nrows * 9) >> 2;
        const float4* src = (const float4*)(X + (size_t)blk0 * 9);
        for (int t = threadIdx.x; t < nf4; t += 256)
            ((float4*)sX)[t] = src[t];
    }
    __syncthreads();

    int i = blk0 + threadIdx.x;
    double local = 0.0;
    if (i < NVEH) {
        const float* row = sX + threadIdx.x * 9;  // stride-9 LDS: 2-way alias = free
        float x0 = row[0], x1 = row[1], psi = row[2], v = row[3];
        float p4 = row[4], p5 = row[5];
        float2 yrv = ((const float2*)yr)[i];
        float2 ypv = ((const float2*)yp)[i];
        float yr0 = yrv.x, yr1 = yrv.y, yp0 = ypv.x, yp1 = ypv.y;

        // vehicle dynamics (psi_t never consumed downstream -> skipped)
        float xt = x0 + v * cosf(psi) * DT;
        float yt = x1 + v * sinf(psi) * DT;
        float vt = 0.99f * v + yr0 * DT;

        // masks
        float dx = xt - p4, dy = yt - p5;
        bool m1 = (sqrtf(dx * dx + dy * dy) - (PARK_C + fabsf(v))) > 0.0f;
        bool m2 = fabsf(vt) >= (DEFV_C - 1e-5f);
        float sg = (vt > 0.0f) ? 1.0f : ((vt < 0.0f) ? -1.0f : 0.0f);
        bool m3 = sg * (yr0 - yp0) <= 1e-5f;
        bool msk = m1 && m2 && m3;
        maskArr[i] = msk ? 1.0f : 0.0f;
        if (msk) {
            segdiff[i] = 0.0f;                   // only masked entries are ever accumulated/read
            int idx = atomicAdd(countp, 1);
            if (idx < LIST_CAP) ids[idx] = i;
        }

        // edge-independent loss terms
        float t1 = (yr1 - yp1) * 1.25f;          // / BOUND1 (0.8)
        float l1 = t1 * t1;
        float t2 = yr0 - yp0;                    // / BOUND0 (1.0)
        float l21 = t2 * t2;
        float2 bev = ((const float2*)be)[i];
        float b1s = bev.y * 1.25f;
        float l3 = bev.x * bev.x + b1s * b1s;

        local = (double)l1 + (double)((msk ? 0.0f : 1.0f) * l21) + 0.1 * (double)l3;
    }
    // wave-level double reduction -> ONE PLAIN STORE per wave (no atomics)
    for (int off = 32; off > 0; off >>= 1)
        local += __shfl_down(local, off, 64);
    if ((threadIdx.x & 63) == 0)
        partials[blockIdx.x * 4 + (threadIdx.x >> 6)] = local;
}

__device__ __forceinline__ void edge_compute(
    int a, int b,
    const float* __restrict__ X, const float* __restrict__ yr,
    const float* __restrict__ yp, float* __restrict__ segdiff)
{
    float pax, pay, rax, ray, ga, ha;
    float pbx, pby, rbx, rby, gb, hb;
    node_state(a, X, yr, yp, pax, pay, rax, ray, ga, ha);
    node_state(b, X, yr, yp, pbx, pby, rbx, rby, gb, hb);

    float base = ga + hb;    // g[a] + h[b]

    float dxp = pax - pbx, dyp = pay - pby;
    float dp = sqrtf(dxp * dxp + dyp * dyp);
    float lcp = fmaxf(base - dp, 0.0f);

    float dxr = rax - rbx, dyr = ray - rby;
    float dr = sqrtf(dxr * dxr + dyr * dyr);
    float lcr = fmaxf(base - dr, 0.0f);

    float diff = (lcp * lcp + lcp) - (lcr * lcr + lcr);
    if (diff != 0.0f)
        atomicAdd(segdiff + b, diff);
}

__global__ __launch_bounds__(256) void edge_kernel(
    const int* __restrict__ e0p, const int* __restrict__ e1p,
    const float* __restrict__ X, const float* __restrict__ yr,
    const float* __restrict__ yp, const float* __restrict__ maskArr,
    float* __restrict__ segdiff,
    const int* __restrict__ countp, const int* __restrict__ ids)
{
    __shared__ int s_ids[LIST_CAP];
    int cnt = *countp;
    int base = (blockIdx.x * 256 + threadIdx.x) * 4;   // 4 edges per thread

    if (cnt == 0) return;                              // whole e1 stream is dead

    if (cnt <= LIST_CAP) {
        for (int t = threadIdx.x; t < cnt; t += 256) s_ids[t] = ids[t];
        __syncthreads();
        vint4 bv = __builtin_nontemporal_load((const vint4*)(e1p + base));

        if (cnt <= REG_USE) {
            // branchless registerized membership test (typical: cnt ~ a few)
            int idr[REG_USE];
#pragma unroll
            for (int j = 0; j < REG_USE; ++j)
                idr[j] = (j < cnt) ? s_ids[j] : -1;

            int bs[4] = {bv.x, bv.y, bv.z, bv.w};
#pragma unroll
            for (int k = 0; k < 4; ++k) {
                int b = bs[k];
                bool h = false;
#pragma unroll
                for (int j = 0; j < REG_USE; ++j) h |= (b == idr[j]);
                if (h) {
                    int a = e0p[base + k];
                    edge_compute(a, b, X, yr, yp, segdiff);
                }
            }
        } else {
            // rare: LDS membership loop over up to 4096 ids
            int bs[4] = {bv.x, bv.y, bv.z, bv.w};
#pragma unroll
            for (int k = 0; k < 4; ++k) {
                int b = bs[k];
                bool h = false;
                for (int j = 0; j < cnt; ++j) h |= (b == s_ids[j]);
                if (h) {
                    int a = e0p[base + k];
                    edge_compute(a, b, X, yr, yp, segdiff);
                }
            }
        }
    } else {
        // robust fallback: per-edge mask gather (statistically never taken)
        for (int k = 0; k < 4; ++k) {
            int b = e1p[base + k];
            if (b < NVEH && maskArr[b] != 0.0f) {
                int a = e0p[base + k];
                edge_compute(a, b, X, yr, yp, segdiff);
            }
        }
    }
}

__global__ __launch_bounds__(256) void finish_kernel(
    const double* __restrict__ partials,
    const float* __restrict__ X, const float* __restrict__ yr,
    const float* __restrict__ yp,
    const float* __restrict__ segdiff, const float* __restrict__ maskArr,
    const int* __restrict__ countp, const int* __restrict__ ids,
    float* __restrict__ out)
{
    int tid = threadIdx.x;
    // 4 independent accumulators for load ILP over the partials
    double s0 = 0.0, s1 = 0.0, s2 = 0.0, s3 = 0.0;
    for (int j = tid; j < MASK_WAVES; j += 1024) {
        s0 += partials[j];
        if (j + 256 < MASK_WAVES) s1 += partials[j + 256];
        if (j + 512 < MASK_WAVES) s2 += partials[j + 512];
        if (j + 768 < MASK_WAVES) s3 += partials[j + 768];
    }
    double s = (s0 + s1) + (s2 + s3);

    int cnt = *countp;
    if (cnt <= LIST_CAP) {
        for (int j = tid; j < cnt; j += 256) {
            int i = ids[j];
            float px, py, rx, ry, g, h;
            node_state(i, X, yr, yp, px, py, rx, ry, g, h);
            float bd = sqrtf(px * px + py * py) - sqrtf(rx * rx + ry * ry);
            float d = bd + segdiff[i];
            s += (double)((d >= 0.0f) ? (d * d + d) : d);
        }
    } else {
        // slow-but-correct fallback
        for (int i = tid; i < NVEH; i += 256) {
            if (maskArr[i] != 0.0f) {
                float px, py, rx, ry, g, h;
                node_state(i, X, yr, yp, px, py, rx, ry, g, h);
                float bd = sqrtf(px * px + py * py) - sqrtf(rx * rx + ry * ry);
                float d = bd + segdiff[i];
                s += (double)((d >= 0.0f) ? (d * d + d) : d);
            }
        }
    }

    // block reduction (4 waves)
    __shared__ double red[4];
    for (int off = 32; off > 0; off >>= 1)
        s += __shfl_down(s, off, 64);
    if ((tid & 63) == 0) red[tid >> 6] = s;
    __syncthreads();
    if (tid == 0) {
        double t = red[0] + red[1] + red[2] + red[3];
        out[0] = (float)(t * (1.0 / (double)NVEH));
    }
}

extern "C" void kernel_launch(void* const* d_in, const int* in_sizes, int n_in,
                              void* d_out, int out_size, void* d_ws, size_t ws_size,
                              hipStream_t stream) {
    const float* yp = (const float*)d_in[0];   // y_pred  (NV,2)
    const float* yr = (const float*)d_in[1];   // y_ref   (NV,2)
    const float* X  = (const float*)d_in[2];   // X_cur   (N,9)
    const int*   ed = (const int*)d_in[3];     // edges   (2,E)
    const float* be = (const float*)d_in[4];   // be_static (NV,2)
    float* out = (float*)d_out;

    char* ws = (char*)d_ws;
    float*  maskArr  = (float*) (ws + 0);
    float*  segdiff  = (float*) (ws + 1600000);
    int*    countp   = (int*)   (ws + 3200000);
    int*    ids      = (int*)   (ws + 3200016);
    double* partials = (double*)(ws + 3216400);

    // only the 4-byte counter needs pre-zeroing
    (void)hipMemsetAsync(countp, 0, 4, stream);

    mask_kernel<<<MASK_BLOCKS, 256, 0, stream>>>(
        yp, yr, X, be, maskArr, segdiff, countp, ids, partials);

    edge_kernel<<<NEDGE / (256 * 4), 256, 0, stream>>>(
        ed, ed + NEDGE, X, yr, yp, maskArr, segdiff, countp, ids);

    finish_kernel<<<1, 256, 0, stream>>>(
        partials, X, yr, yp, segdiff, maskArr, countp, ids, out);
}